// Round 1
// baseline (600.521 us; speedup 1.0000x reference)
//
#include <hip/hip_runtime.h>

#define NN 8192
#define NVEC ((long long)NN * NN / 4)   // 16,777,216 float4 elements
#define BLOCKS 2048
#define THREADS 256

__global__ __launch_bounds__(THREADS) void fused_update_reduce(
    const float* __restrict__ a,      // [N] neural_activities
    const float* __restrict__ W,      // [N,N] connection_matrix
    const float* __restrict__ Cin,    // [N,N] correlation_matrix
    float* __restrict__ Cout,         // [N,N] output C
    double* __restrict__ partials)    // [BLOCKS*3]
{
    const float decay = 0.9f;
    const float om    = 0.1f;   // jnp.float32(1.0 - 0.9) == 0.1f

    double s_abs = 0.0, s_w = 0.0, s_cw = 0.0;

    const long long stride = (long long)gridDim.x * blockDim.x;
    for (long long v = (long long)blockIdx.x * blockDim.x + threadIdx.x;
         v < NVEC; v += stride) {
        const long long base = v * 4;
        const int row  = (int)(base >> 13);        // N = 8192 = 2^13
        const int col0 = (int)(base & (NN - 1));   // multiple of 4

        const float4 c4 = ((const float4*)Cin)[v];
        const float4 w4 = ((const float4*)W)[v];
        const float4 a4 = *(const float4*)(a + col0);
        const float  ar = a[row];

        float o0 = decay * c4.x + om * ar * a4.x;
        float o1 = decay * c4.y + om * ar * a4.y;
        float o2 = decay * c4.z + om * ar * a4.z;
        float o3 = decay * c4.w + om * ar * a4.w;

        // diagonal untouched
        if (row == col0)     o0 = c4.x;
        if (row == col0 + 1) o1 = c4.y;
        if (row == col0 + 2) o2 = c4.z;
        if (row == col0 + 3) o3 = c4.w;

        float4 out4 = make_float4(o0, o1, o2, o3);
        ((float4*)Cout)[v] = out4;

        const float ab0 = fabsf(o0), ab1 = fabsf(o1),
                    ab2 = fabsf(o2), ab3 = fabsf(o3);

        s_abs += (double)((ab0 + ab1) + (ab2 + ab3));
        s_w   += (double)((w4.x + w4.y) + (w4.z + w4.w));
        s_cw  += (double)((ab0 * w4.x + ab1 * w4.y) + (ab2 * w4.z + ab3 * w4.w));
    }

    // wave-level reduction (64 lanes)
    for (int off = 32; off > 0; off >>= 1) {
        s_abs += __shfl_down(s_abs, off, 64);
        s_w   += __shfl_down(s_w,   off, 64);
        s_cw  += __shfl_down(s_cw,  off, 64);
    }

    __shared__ double sh[3][THREADS / 64];
    const int lane = threadIdx.x & 63;
    const int wv   = threadIdx.x >> 6;
    if (lane == 0) {
        sh[0][wv] = s_abs; sh[1][wv] = s_w; sh[2][wv] = s_cw;
    }
    __syncthreads();
    if (threadIdx.x == 0) {
        double t0 = 0.0, t1 = 0.0, t2 = 0.0;
        #pragma unroll
        for (int i = 0; i < THREADS / 64; ++i) {
            t0 += sh[0][i]; t1 += sh[1][i]; t2 += sh[2][i];
        }
        partials[blockIdx.x * 3 + 0] = t0;
        partials[blockIdx.x * 3 + 1] = t1;
        partials[blockIdx.x * 3 + 2] = t2;
    }
}

__global__ __launch_bounds__(256) void finalize_scalars(
    const double* __restrict__ partials,   // [BLOCKS*3]
    const float* __restrict__ coh_in,      // [1]
    const float* __restrict__ integ_in,    // [1]
    float* __restrict__ out_scalars)       // [3]: coherence, integration, synchrony
{
    double s_abs = 0.0, s_w = 0.0, s_cw = 0.0;
    for (int i = threadIdx.x; i < BLOCKS; i += blockDim.x) {
        s_abs += partials[i * 3 + 0];
        s_w   += partials[i * 3 + 1];
        s_cw  += partials[i * 3 + 2];
    }
    for (int off = 32; off > 0; off >>= 1) {
        s_abs += __shfl_down(s_abs, off, 64);
        s_w   += __shfl_down(s_w,   off, 64);
        s_cw  += __shfl_down(s_cw,  off, 64);
    }
    __shared__ double sh[3][4];
    const int lane = threadIdx.x & 63;
    const int wv   = threadIdx.x >> 6;
    if (lane == 0) { sh[0][wv] = s_abs; sh[1][wv] = s_w; sh[2][wv] = s_cw; }
    __syncthreads();
    if (threadIdx.x == 0) {
        double t_abs = 0.0, t_w = 0.0, t_cw = 0.0;
        #pragma unroll
        for (int i = 0; i < 4; ++i) { t_abs += sh[0][i]; t_w += sh[1][i]; t_cw += sh[2][i]; }

        const float decay = 0.9f, om = 0.1f;
        const double n_conn = (double)NN * (double)(NN - 1);
        const double n_tot  = (double)NN * (double)NN;

        const float coherence = decay * coh_in[0] + om * (float)(t_abs / n_conn);
        float integration = integ_in[0];
        if (t_w > 0.0) {
            integration = decay * integ_in[0] + om * (float)(t_cw / t_w);
        }
        const float synchrony = (float)(t_abs / n_tot);

        out_scalars[0] = coherence;
        out_scalars[1] = integration;
        out_scalars[2] = synchrony;
    }
}

extern "C" void kernel_launch(void* const* d_in, const int* in_sizes, int n_in,
                              void* d_out, int out_size, void* d_ws, size_t ws_size,
                              hipStream_t stream) {
    const float* a     = (const float*)d_in[0];   // neural_activities [N]
    const float* W     = (const float*)d_in[1];   // connection_matrix [N,N]
    const float* Cin   = (const float*)d_in[2];   // correlation_matrix [N,N]
    const float* coh   = (const float*)d_in[3];   // coherence_strength [1]
    const float* integ = (const float*)d_in[4];   // integration_measure [1]

    float*  Cout     = (float*)d_out;                       // [N,N]
    float*  scalars  = (float*)d_out + (long long)NN * NN;  // [3]
    double* partials = (double*)d_ws;                       // [BLOCKS*3]

    fused_update_reduce<<<BLOCKS, THREADS, 0, stream>>>(a, W, Cin, Cout, partials);
    finalize_scalars<<<1, 256, 0, stream>>>(partials, coh, integ, scalars);
}